// Round 1
// baseline (1083.792 us; speedup 1.0000x reference)
//
#include <hip/hip_runtime.h>
#include <hip/hip_bf16.h>
#include <math.h>

// GAT layer: xh = x@W; per-edge attention softmax grouped by dst (with self
// loops); weighted scatter-add; BatchNorm (batch stats); residual +x.
// Strategy: CSR-by-dst build (count/scan/fill) -> one wave per node does
// two-pass softmax + register-accumulated gather (no output atomics).

#define N_NODES 100000
#define N_EDGES 1600000
#define D_IN    256
#define HEADS   8
#define D_HEAD  32
#define NCH     256           // HEADS*D_HEAD
#define NEG_SLOPE 0.2f
#define BN_EPS  1e-5f

// ---- workspace layout (bytes) ----
// xh      [N,256] f32 : 102,400,000
// a_src   [N,8]   f32 :   3,200,000
// a_dst   [N,8]   f32 :   3,200,000
// row_ptr [N+1]   i32 :     400,004 (padded to 256)
// cursor  [N]     i32 :     400,000
// counts  [N]     i32 :     400,000
// csr_src [E]     i32 :   6,400,000
// accum   [512]   f32 :       2,048
// total ~116.5 MB
#define OFF_XH      0
#define OFF_ASRC    102400000
#define OFF_ADST    105600000
#define OFF_ROWPTR  108800000
#define OFF_CURSOR  109200256
#define OFF_COUNTS  109600256
#define OFF_CSRSRC  110000256
#define OFF_ACCUM   116400256

__device__ __forceinline__ float leaky(float v) {
    return v > 0.f ? v : NEG_SLOPE * v;
}

// ---------------- SGEMM: xh = x @ W  (fp32, 128x128 tile, 8x8/thread) ------
__global__ __launch_bounds__(256) void sgemm_xw(const float* __restrict__ A,
                                                const float* __restrict__ B,
                                                float* __restrict__ C) {
    __shared__ float As[8][132];   // [k][row], +4 pad
    __shared__ float Bs[8][128];   // [k][col]
    const int row0 = blockIdx.x * 128;
    const int col0 = blockIdx.y * 128;
    const int tid = threadIdx.x;
    const int ty = tid >> 4, tx = tid & 15;

    float acc[8][8];
#pragma unroll
    for (int m = 0; m < 8; ++m)
#pragma unroll
        for (int n = 0; n < 8; ++n) acc[m][n] = 0.f;

    const int ar = tid >> 1, ac4 = (tid & 1) * 4;     // A tile 128x8
    const int br = tid >> 5, bc4 = (tid & 31) * 4;    // B tile 8x128

    for (int k0 = 0; k0 < 256; k0 += 8) {
        float4 av = make_float4(0.f, 0.f, 0.f, 0.f);
        const int arow = row0 + ar;
        if (arow < N_NODES)
            av = *(const float4*)&A[(size_t)arow * 256 + k0 + ac4];
        As[ac4 + 0][ar] = av.x;
        As[ac4 + 1][ar] = av.y;
        As[ac4 + 2][ar] = av.z;
        As[ac4 + 3][ar] = av.w;
        float4 bv = *(const float4*)&B[(size_t)(k0 + br) * 256 + col0 + bc4];
        *(float4*)&Bs[br][bc4] = bv;
        __syncthreads();
#pragma unroll
        for (int kk = 0; kk < 8; ++kk) {
            float a[8], b[8];
            *(float4*)&a[0] = *(float4*)&As[kk][ty * 8];
            *(float4*)&a[4] = *(float4*)&As[kk][ty * 8 + 4];
            *(float4*)&b[0] = *(float4*)&Bs[kk][tx * 8];
            *(float4*)&b[4] = *(float4*)&Bs[kk][tx * 8 + 4];
#pragma unroll
            for (int m = 0; m < 8; ++m)
#pragma unroll
                for (int n = 0; n < 8; ++n)
                    acc[m][n] = fmaf(a[m], b[n], acc[m][n]);
        }
        __syncthreads();
    }
#pragma unroll
    for (int m = 0; m < 8; ++m) {
        const int row = row0 + ty * 8 + m;
        if (row < N_NODES) {
            float* cp = &C[(size_t)row * 256 + col0 + tx * 8];
            *(float4*)cp       = make_float4(acc[m][0], acc[m][1], acc[m][2], acc[m][3]);
            *(float4*)(cp + 4) = make_float4(acc[m][4], acc[m][5], acc[m][6], acc[m][7]);
        }
    }
}

// ------------- a_src/a_dst: one wave per node, 8-lane head groups ----------
__global__ __launch_bounds__(256) void att_vec(const float* __restrict__ xh,
                                               const float* __restrict__ att_src,
                                               const float* __restrict__ att_dst,
                                               float* __restrict__ a_src,
                                               float* __restrict__ a_dst) {
    const int wid = (blockIdx.x * blockDim.x + threadIdx.x) >> 6;
    const int lane = threadIdx.x & 63;
    if (wid >= N_NODES) return;
    const float4 xv = *(const float4*)&xh[(size_t)wid * 256 + lane * 4];
    const int h = lane >> 3;
    const int doff = (lane & 7) * 4;
    const float4 sv = *(const float4*)&att_src[h * 32 + doff];
    const float4 dv = *(const float4*)&att_dst[h * 32 + doff];
    float ss = xv.x * sv.x + xv.y * sv.y + xv.z * sv.z + xv.w * sv.w;
    float sd = xv.x * dv.x + xv.y * dv.y + xv.z * dv.z + xv.w * dv.w;
#pragma unroll
    for (int m = 1; m < 8; m <<= 1) {
        ss += __shfl_xor(ss, m);
        sd += __shfl_xor(sd, m);
    }
    if ((lane & 7) == 0) {
        a_src[wid * 8 + h] = ss;
        a_dst[wid * 8 + h] = sd;
    }
}

// ---------------- CSR build ----------------
__global__ void count_edges(const int* __restrict__ ei, int* __restrict__ counts) {
    const int e = blockIdx.x * blockDim.x + threadIdx.x;
    if (e < N_EDGES) atomicAdd(&counts[ei[N_EDGES + e]], 1);
}

__global__ __launch_bounds__(1024) void scan_kernel(const int* __restrict__ counts,
                                                    int* __restrict__ row_ptr,
                                                    int* __restrict__ cursor) {
    __shared__ int sdata[1024];
    __shared__ int s_off;
    const int tid = threadIdx.x;
    if (tid == 0) s_off = 0;
    __syncthreads();
    for (int base = 0; base < N_NODES; base += 1024) {
        const int idx = base + tid;
        const int v = (idx < N_NODES) ? counts[idx] : 0;
        sdata[tid] = v;
        __syncthreads();
#pragma unroll
        for (int off = 1; off < 1024; off <<= 1) {
            const int add = (tid >= off) ? sdata[tid - off] : 0;
            __syncthreads();
            sdata[tid] += add;
            __syncthreads();
        }
        const int excl = sdata[tid] - v + s_off;
        if (idx < N_NODES) { row_ptr[idx] = excl; cursor[idx] = excl; }
        __syncthreads();
        if (tid == 0) s_off += sdata[1023];
        __syncthreads();
    }
    if (tid == 0) row_ptr[N_NODES] = s_off;
}

__global__ void fill_csr(const int* __restrict__ ei, int* __restrict__ cursor,
                         int* __restrict__ csr_src) {
    const int e = blockIdx.x * blockDim.x + threadIdx.x;
    if (e < N_EDGES) {
        const int s = ei[e];
        const int d = ei[N_EDGES + e];
        const int pos = atomicAdd(&cursor[d], 1);
        csr_src[pos] = s;
    }
}

// ---------------- aggregate: one wave per node, two-pass softmax ----------
__global__ __launch_bounds__(256) void aggregate(const float* __restrict__ xh,
                                                 const float* __restrict__ a_src,
                                                 const float* __restrict__ a_dst,
                                                 const int* __restrict__ row_ptr,
                                                 const int* __restrict__ csr_src,
                                                 const float* __restrict__ bias,
                                                 float* __restrict__ outbuf) {
    const int i = (blockIdx.x * blockDim.x + threadIdx.x) >> 6;
    const int lane = threadIdx.x & 63;
    if (i >= N_NODES) return;
    const int beg = row_ptr[i], end = row_ptr[i + 1];

    // pass 1: lane handles head (lane&7), neighbor subset (lane>>3) stride 8
    const int h1 = lane & 7, sub = lane >> 3;
    const float ad1 = a_dst[i * 8 + h1];
    const float as1 = a_src[i * 8 + h1];
    const float eself = leaky(as1 + ad1);
    float mx = (sub == 0) ? eself : -INFINITY;
    for (int n = beg + sub; n < end; n += 8) {
        const int j = csr_src[n];
        mx = fmaxf(mx, leaky(a_src[j * 8 + h1] + ad1));
    }
#pragma unroll
    for (int m = 8; m < 64; m <<= 1) mx = fmaxf(mx, __shfl_xor(mx, m));
    float sm = (sub == 0) ? __expf(eself - mx) : 0.f;
    for (int n = beg + sub; n < end; n += 8) {
        const int j = csr_src[n];
        sm += __expf(leaky(a_src[j * 8 + h1] + ad1) - mx);
    }
#pragma unroll
    for (int m = 8; m < 64; m <<= 1) sm += __shfl_xor(sm, m);

    // remap: lane now owns channels 4*lane..4*lane+3 -> head h2 = lane>>3
    const int h2 = lane >> 3;
    const float m2 = __shfl(mx, h2);   // lane q (q<8) holds head q
    const float s2 = __shfl(sm, h2);
    const float inv = 1.0f / s2;
    const float ad2 = a_dst[i * 8 + h2];
    const float as2 = a_src[i * 8 + h2];

    const float wself = __expf(leaky(as2 + ad2) - m2) * inv;
    const float4 xv = *(const float4*)&xh[(size_t)i * 256 + lane * 4];
    float4 acc;
    acc.x = wself * xv.x; acc.y = wself * xv.y;
    acc.z = wself * xv.z; acc.w = wself * xv.w;

    for (int n = beg; n < end; ++n) {
        const int j = csr_src[n];
        const float w = __expf(leaky(a_src[j * 8 + h2] + ad2) - m2) * inv;
        const float4 v = *(const float4*)&xh[(size_t)j * 256 + lane * 4];
        acc.x = fmaf(w, v.x, acc.x);
        acc.y = fmaf(w, v.y, acc.y);
        acc.z = fmaf(w, v.z, acc.z);
        acc.w = fmaf(w, v.w, acc.w);
    }
    const float4 bv = *(const float4*)&bias[lane * 4];
    acc.x += bv.x; acc.y += bv.y; acc.z += bv.z; acc.w += bv.w;
    *(float4*)&outbuf[(size_t)i * 256 + lane * 4] = acc;
}

// ---------------- BatchNorm stats: per-channel sum / sumsq ----------------
__global__ __launch_bounds__(256) void bn_stats(const float* __restrict__ outbuf,
                                                float* __restrict__ accum) {
    const int c = threadIdx.x;   // 256 channels
    float s = 0.f, s2 = 0.f;
    for (int r = blockIdx.x; r < N_NODES; r += gridDim.x) {
        const float v = outbuf[(size_t)r * 256 + c];
        s += v; s2 += v * v;
    }
    atomicAdd(&accum[c], s);
    atomicAdd(&accum[256 + c], s2);
}

// ---------------- BN normalize + residual (in-place on d_out) -------------
__global__ __launch_bounds__(256) void bn_final(float* __restrict__ out,
                                                const float* __restrict__ x,
                                                const float* __restrict__ accum,
                                                const float* __restrict__ gamma,
                                                const float* __restrict__ beta) {
    const size_t total4 = (size_t)N_NODES * 64;
    const size_t stride = (size_t)gridDim.x * blockDim.x;
    const float invN = 1.0f / (float)N_NODES;
    for (size_t f = blockIdx.x * blockDim.x + threadIdx.x; f < total4; f += stride) {
        const int c4 = ((int)(f & 63)) * 4;
        float4 v = *(float4*)&out[f * 4];
        const float4 xv = *(const float4*)&x[f * 4];
        const float4 sv = *(const float4*)&accum[c4];
        const float4 qv = *(const float4*)&accum[256 + c4];
        const float4 gv = *(const float4*)&gamma[c4];
        const float4 bv = *(const float4*)&beta[c4];
        float mean, var;
        mean = sv.x * invN; var = qv.x * invN - mean * mean;
        v.x = (v.x - mean) * rsqrtf(var + BN_EPS) * gv.x + bv.x + xv.x;
        mean = sv.y * invN; var = qv.y * invN - mean * mean;
        v.y = (v.y - mean) * rsqrtf(var + BN_EPS) * gv.y + bv.y + xv.y;
        mean = sv.z * invN; var = qv.z * invN - mean * mean;
        v.z = (v.z - mean) * rsqrtf(var + BN_EPS) * gv.z + bv.z + xv.z;
        mean = sv.w * invN; var = qv.w * invN - mean * mean;
        v.w = (v.w - mean) * rsqrtf(var + BN_EPS) * gv.w + bv.w + xv.w;
        *(float4*)&out[f * 4] = v;
    }
}

extern "C" void kernel_launch(void* const* d_in, const int* in_sizes, int n_in,
                              void* d_out, int out_size, void* d_ws, size_t ws_size,
                              hipStream_t stream) {
    const float* x       = (const float*)d_in[0];
    const int*   ei      = (const int*)d_in[1];
    const float* W       = (const float*)d_in[2];
    const float* att_src = (const float*)d_in[3];
    const float* att_dst = (const float*)d_in[4];
    const float* bias    = (const float*)d_in[5];
    const float* gamma   = (const float*)d_in[6];
    const float* beta    = (const float*)d_in[7];
    float* out = (float*)d_out;

    char* ws = (char*)d_ws;
    float* xh      = (float*)(ws + OFF_XH);
    float* a_src   = (float*)(ws + OFF_ASRC);
    float* a_dst   = (float*)(ws + OFF_ADST);
    int*   row_ptr = (int*)(ws + OFF_ROWPTR);
    int*   cursor  = (int*)(ws + OFF_CURSOR);
    int*   counts  = (int*)(ws + OFF_COUNTS);
    int*   csr_src = (int*)(ws + OFF_CSRSRC);
    float* accum   = (float*)(ws + OFF_ACCUM);

    hipMemsetAsync(counts, 0, N_NODES * sizeof(int), stream);
    hipMemsetAsync(accum, 0, 512 * sizeof(float), stream);

    dim3 gemm_grid((N_NODES + 127) / 128, 2);
    sgemm_xw<<<gemm_grid, 256, 0, stream>>>(x, W, xh);

    att_vec<<<(N_NODES * 64 + 255) / 256, 256, 0, stream>>>(xh, att_src, att_dst,
                                                            a_src, a_dst);

    count_edges<<<(N_EDGES + 255) / 256, 256, 0, stream>>>(ei, counts);
    scan_kernel<<<1, 1024, 0, stream>>>(counts, row_ptr, cursor);
    fill_csr<<<(N_EDGES + 255) / 256, 256, 0, stream>>>(ei, cursor, csr_src);

    aggregate<<<(N_NODES * 64 + 255) / 256, 256, 0, stream>>>(
        xh, a_src, a_dst, row_ptr, csr_src, bias, out);

    bn_stats<<<512, 256, 0, stream>>>(out, accum);
    bn_final<<<2048, 256, 0, stream>>>(out, x, accum, gamma, beta);
}

// Round 3
// 912.766 us; speedup vs baseline: 1.1874x; 1.1874x over previous
//
#include <hip/hip_runtime.h>
#include <hip/hip_bf16.h>
#include <math.h>

// GAT layer: xh = x@W; per-edge attention softmax grouped by dst (with self
// loops); weighted scatter-add; BatchNorm (batch stats); residual +x.
// R3: fix pass-A inactive-lane shfl (ds_bpermute returns 0 from inactive
// lanes on divergent trip counts) -> direct csr_src reads in pass A.

#define N_NODES 100000
#define N_EDGES 1600000
#define D_IN    256
#define HEADS   8
#define D_HEAD  32
#define NCH     256           // HEADS*D_HEAD
#define NEG_SLOPE 0.2f
#define BN_EPS  1e-5f

// ---- workspace layout (bytes) ----
#define OFF_XH      0
#define OFF_ASRC    102400000
#define OFF_ADST    105600000
#define OFF_ROWPTR  108800000
#define OFF_CURSOR  109200256
#define OFF_COUNTS  109600256
#define OFF_CSRSRC  110000256
#define OFF_ACCUM   116400256
#define OFF_BSUMS   116402304
#define OFF_BOFF    116402816

__device__ __forceinline__ float leaky(float v) {
    return v > 0.f ? v : NEG_SLOPE * v;
}

// ---------------- SGEMM: xh = x @ W  (fp32, 128x128 tile, dbuf LDS) --------
__global__ __launch_bounds__(256) void sgemm_xw(const float* __restrict__ A,
                                                const float* __restrict__ B,
                                                float* __restrict__ C) {
    __shared__ float As[2][8][132];   // [buf][k][row], +4 pad
    __shared__ float Bs[2][8][128];   // [buf][k][col]
    const int row0 = blockIdx.x * 128;
    const int col0 = blockIdx.y * 128;
    const int tid = threadIdx.x;
    const int ty = tid >> 4, tx = tid & 15;

    float acc[8][8];
#pragma unroll
    for (int m = 0; m < 8; ++m)
#pragma unroll
        for (int n = 0; n < 8; ++n) acc[m][n] = 0.f;

    const int ar = tid >> 1, ac4 = (tid & 1) * 4;     // A tile 128x8
    const int br = tid >> 5, bc4 = (tid & 31) * 4;    // B tile 8x128
    const int arow = row0 + ar;

    // prologue: tile k0=0 -> LDS[0]
    {
        float4 av = make_float4(0.f, 0.f, 0.f, 0.f);
        if (arow < N_NODES) av = *(const float4*)&A[(size_t)arow * 256 + ac4];
        As[0][ac4 + 0][ar] = av.x;
        As[0][ac4 + 1][ar] = av.y;
        As[0][ac4 + 2][ar] = av.z;
        As[0][ac4 + 3][ar] = av.w;
        *(float4*)&Bs[0][br][bc4] = *(const float4*)&B[(size_t)br * 256 + col0 + bc4];
    }
    __syncthreads();

    int buf = 0;
    for (int k0 = 0; k0 < 256; k0 += 8) {
        const bool more = (k0 + 8) < 256;
        float4 av2 = make_float4(0.f, 0.f, 0.f, 0.f), bv2;
        if (more) {
            if (arow < N_NODES)
                av2 = *(const float4*)&A[(size_t)arow * 256 + k0 + 8 + ac4];
            bv2 = *(const float4*)&B[(size_t)(k0 + 8 + br) * 256 + col0 + bc4];
        }
#pragma unroll
        for (int kk = 0; kk < 8; ++kk) {
            float a[8], b[8];
            *(float4*)&a[0] = *(float4*)&As[buf][kk][ty * 8];
            *(float4*)&a[4] = *(float4*)&As[buf][kk][ty * 8 + 4];
            *(float4*)&b[0] = *(float4*)&Bs[buf][kk][tx * 8];
            *(float4*)&b[4] = *(float4*)&Bs[buf][kk][tx * 8 + 4];
#pragma unroll
            for (int m = 0; m < 8; ++m)
#pragma unroll
                for (int n = 0; n < 8; ++n)
                    acc[m][n] = fmaf(a[m], b[n], acc[m][n]);
        }
        if (more) {
            const int nb = buf ^ 1;
            As[nb][ac4 + 0][ar] = av2.x;
            As[nb][ac4 + 1][ar] = av2.y;
            As[nb][ac4 + 2][ar] = av2.z;
            As[nb][ac4 + 3][ar] = av2.w;
            *(float4*)&Bs[nb][br][bc4] = bv2;
            __syncthreads();
            buf = nb;
        }
    }
#pragma unroll
    for (int m = 0; m < 8; ++m) {
        const int row = row0 + ty * 8 + m;
        if (row < N_NODES) {
            float* cp = &C[(size_t)row * 256 + col0 + tx * 8];
            *(float4*)cp       = make_float4(acc[m][0], acc[m][1], acc[m][2], acc[m][3]);
            *(float4*)(cp + 4) = make_float4(acc[m][4], acc[m][5], acc[m][6], acc[m][7]);
        }
    }
}

// ------------- a_src/a_dst: one wave per node, 8-lane head groups ----------
__global__ __launch_bounds__(256) void att_vec(const float* __restrict__ xh,
                                               const float* __restrict__ att_src,
                                               const float* __restrict__ att_dst,
                                               float* __restrict__ a_src,
                                               float* __restrict__ a_dst) {
    const int wid = (blockIdx.x * blockDim.x + threadIdx.x) >> 6;
    const int lane = threadIdx.x & 63;
    if (wid >= N_NODES) return;
    const float4 xv = *(const float4*)&xh[(size_t)wid * 256 + lane * 4];
    const int h = lane >> 3;
    const int doff = (lane & 7) * 4;
    const float4 sv = *(const float4*)&att_src[h * 32 + doff];
    const float4 dv = *(const float4*)&att_dst[h * 32 + doff];
    float ss = xv.x * sv.x + xv.y * sv.y + xv.z * sv.z + xv.w * sv.w;
    float sd = xv.x * dv.x + xv.y * dv.y + xv.z * dv.z + xv.w * dv.w;
#pragma unroll
    for (int m = 1; m < 8; m <<= 1) {
        ss += __shfl_xor(ss, m);
        sd += __shfl_xor(sd, m);
    }
    if ((lane & 7) == 0) {
        a_src[wid * 8 + h] = ss;
        a_dst[wid * 8 + h] = sd;
    }
}

// ---------------- CSR build ----------------
__global__ void count_edges(const int* __restrict__ ei, int* __restrict__ counts) {
    const int e = blockIdx.x * blockDim.x + threadIdx.x;
    if (e < N_EDGES) atomicAdd(&counts[ei[N_EDGES + e]], 1);
}

// phase 1: per-block (1024) exclusive scan, write block sums
__global__ __launch_bounds__(1024) void scan1(const int* __restrict__ counts,
                                              int* __restrict__ row_ptr,
                                              int* __restrict__ bsums) {
    __shared__ int s[1024];
    const int tid = threadIdx.x;
    const int idx = blockIdx.x * 1024 + tid;
    const int v = (idx < N_NODES) ? counts[idx] : 0;
    s[tid] = v;
    __syncthreads();
#pragma unroll
    for (int off = 1; off < 1024; off <<= 1) {
        const int add = (tid >= off) ? s[tid - off] : 0;
        __syncthreads();
        s[tid] += add;
        __syncthreads();
    }
    if (idx < N_NODES) row_ptr[idx] = s[tid] - v;   // exclusive within block
    if (tid == 1023) bsums[blockIdx.x] = s[1023];
}

// phase 2: single small block scans the 98 block sums (exclusive)
__global__ __launch_bounds__(128) void scan2(const int* __restrict__ bsums,
                                             int* __restrict__ boff, int nb) {
    __shared__ int s[128];
    const int tid = threadIdx.x;
    const int v = (tid < nb) ? bsums[tid] : 0;
    s[tid] = v;
    __syncthreads();
#pragma unroll
    for (int off = 1; off < 128; off <<= 1) {
        const int add = (tid >= off) ? s[tid - off] : 0;
        __syncthreads();
        s[tid] += add;
        __syncthreads();
    }
    if (tid < nb) boff[tid] = s[tid] - v;
}

// phase 3: add block offsets, init cursor, finalize row_ptr[N]
__global__ __launch_bounds__(1024) void scan3(int* __restrict__ row_ptr,
                                              int* __restrict__ cursor,
                                              const int* __restrict__ boff) {
    const int idx = blockIdx.x * 1024 + threadIdx.x;
    if (idx < N_NODES) {
        const int r = row_ptr[idx] + boff[blockIdx.x];
        row_ptr[idx] = r;
        cursor[idx] = r;
    }
    if (idx == 0) row_ptr[N_NODES] = N_EDGES;
}

__global__ void fill_csr(const int* __restrict__ ei, int* __restrict__ cursor,
                         int* __restrict__ csr_src) {
    const int e = blockIdx.x * blockDim.x + threadIdx.x;
    if (e < N_EDGES) {
        const int s = ei[e];
        const int d = ei[N_EDGES + e];
        const int pos = atomicAdd(&cursor[d], 1);
        csr_src[pos] = s;
    }
}

// ---------------- aggregate: one wave per node, 2 passes + LDS e-cache ----
// Pass A: gather a_src[j] once per edge (8 heads x 8 edge-subsets across the
// wave), cache logits in LDS, track per-head max. Direct csr_src reads —
// NO shfl here (divergent trip counts; bpermute from inactive lane = 0).
// Pass B: uniform loop over all edges; logits from LDS; accumulate
// unnormalized weighted sum + denominator; normalize at end.
__global__ __launch_bounds__(256) void aggregate(const float* __restrict__ xh,
                                                 const float* __restrict__ a_src,
                                                 const float* __restrict__ a_dst,
                                                 const int* __restrict__ row_ptr,
                                                 const int* __restrict__ csr_src,
                                                 const float* __restrict__ bias,
                                                 float* __restrict__ outbuf) {
    __shared__ float e_cache[4][64 * 8];
    const int wv = threadIdx.x >> 6;
    const int lane = threadIdx.x & 63;
    const int i = blockIdx.x * 4 + wv;      // grid sized exactly: i < N_NODES
    const int beg = row_ptr[i], end = row_ptr[i + 1];
    const int deg = end - beg;

    int j_l = 0;
    if (lane < deg) j_l = csr_src[beg + lane];

    // ---- pass A ----
    const int h1 = lane & 7, sub = lane >> 3;
    const float ad1 = a_dst[i * 8 + h1];
    float mx = (sub == 0) ? leaky(a_src[i * 8 + h1] + ad1) : -INFINITY;
    for (int n = sub; n < deg; n += 8) {
        const int j = csr_src[beg + n];
        const float e = leaky(a_src[j * 8 + h1] + ad1);
        if (n < 64) e_cache[wv][n * 8 + h1] = e;
        mx = fmaxf(mx, e);
    }
#pragma unroll
    for (int m = 8; m < 64; m <<= 1) mx = fmaxf(mx, __shfl_xor(mx, m));
    __syncthreads();

    // ---- pass B (uniform loop: shfl sources always active) ----
    const int h2 = lane >> 3;
    const float m2 = __shfl(mx, h2);
    const float ad2 = a_dst[i * 8 + h2];
    const float as2 = a_src[i * 8 + h2];
    float sm = __expf(leaky(as2 + ad2) - m2);   // self-loop weight
    const float4 xv = *(const float4*)&xh[(size_t)i * 256 + lane * 4];
    float4 acc;
    acc.x = sm * xv.x; acc.y = sm * xv.y;
    acc.z = sm * xv.z; acc.w = sm * xv.w;

#pragma unroll 4
    for (int t = 0; t < deg; ++t) {
        const int js = __shfl(j_l, t & 63);
        const int j = (t < 64) ? js : csr_src[beg + t];
        const float e = (t < 64) ? e_cache[wv][t * 8 + h2]
                                 : leaky(a_src[j * 8 + h2] + ad2);
        const float w = __expf(e - m2);
        sm += w;
        const float4 v = *(const float4*)&xh[(size_t)j * 256 + lane * 4];
        acc.x = fmaf(w, v.x, acc.x);
        acc.y = fmaf(w, v.y, acc.y);
        acc.z = fmaf(w, v.z, acc.z);
        acc.w = fmaf(w, v.w, acc.w);
    }
    const float inv = 1.0f / sm;
    const float4 bv = *(const float4*)&bias[lane * 4];
    acc.x = acc.x * inv + bv.x;
    acc.y = acc.y * inv + bv.y;
    acc.z = acc.z * inv + bv.z;
    acc.w = acc.w * inv + bv.w;
    *(float4*)&outbuf[(size_t)i * 256 + lane * 4] = acc;
}

// ---------------- BatchNorm stats: per-channel sum / sumsq ----------------
__global__ __launch_bounds__(256) void bn_stats(const float* __restrict__ outbuf,
                                                float* __restrict__ accum) {
    const int c = threadIdx.x;   // 256 channels
    float s = 0.f, s2 = 0.f;
    for (int r = blockIdx.x; r < N_NODES; r += gridDim.x) {
        const float v = outbuf[(size_t)r * 256 + c];
        s += v; s2 += v * v;
    }
    atomicAdd(&accum[c], s);
    atomicAdd(&accum[256 + c], s2);
}

// ---------------- BN normalize + residual (in-place on d_out) -------------
__global__ __launch_bounds__(256) void bn_final(float* __restrict__ out,
                                                const float* __restrict__ x,
                                                const float* __restrict__ accum,
                                                const float* __restrict__ gamma,
                                                const float* __restrict__ beta) {
    const size_t total4 = (size_t)N_NODES * 64;
    const size_t stride = (size_t)gridDim.x * blockDim.x;
    const float invN = 1.0f / (float)N_NODES;
    for (size_t f = blockIdx.x * blockDim.x + threadIdx.x; f < total4; f += stride) {
        const int c4 = ((int)(f & 63)) * 4;
        float4 v = *(float4*)&out[f * 4];
        const float4 xv = *(const float4*)&x[f * 4];
        const float4 sv = *(const float4*)&accum[c4];
        const float4 qv = *(const float4*)&accum[256 + c4];
        const float4 gv = *(const float4*)&gamma[c4];
        const float4 bv = *(const float4*)&beta[c4];
        float mean, var;
        mean = sv.x * invN; var = qv.x * invN - mean * mean;
        v.x = (v.x - mean) * rsqrtf(var + BN_EPS) * gv.x + bv.x + xv.x;
        mean = sv.y * invN; var = qv.y * invN - mean * mean;
        v.y = (v.y - mean) * rsqrtf(var + BN_EPS) * gv.y + bv.y + xv.y;
        mean = sv.z * invN; var = qv.z * invN - mean * mean;
        v.z = (v.z - mean) * rsqrtf(var + BN_EPS) * gv.z + bv.z + xv.z;
        mean = sv.w * invN; var = qv.w * invN - mean * mean;
        v.w = (v.w - mean) * rsqrtf(var + BN_EPS) * gv.w + bv.w + xv.w;
        *(float4*)&out[f * 4] = v;
    }
}

extern "C" void kernel_launch(void* const* d_in, const int* in_sizes, int n_in,
                              void* d_out, int out_size, void* d_ws, size_t ws_size,
                              hipStream_t stream) {
    const float* x       = (const float*)d_in[0];
    const int*   ei      = (const int*)d_in[1];
    const float* W       = (const float*)d_in[2];
    const float* att_src = (const float*)d_in[3];
    const float* att_dst = (const float*)d_in[4];
    const float* bias    = (const float*)d_in[5];
    const float* gamma   = (const float*)d_in[6];
    const float* beta    = (const float*)d_in[7];
    float* out = (float*)d_out;

    char* ws = (char*)d_ws;
    float* xh      = (float*)(ws + OFF_XH);
    float* a_src   = (float*)(ws + OFF_ASRC);
    float* a_dst   = (float*)(ws + OFF_ADST);
    int*   row_ptr = (int*)(ws + OFF_ROWPTR);
    int*   cursor  = (int*)(ws + OFF_CURSOR);
    int*   counts  = (int*)(ws + OFF_COUNTS);
    int*   csr_src = (int*)(ws + OFF_CSRSRC);
    float* accum   = (float*)(ws + OFF_ACCUM);
    int*   bsums   = (int*)(ws + OFF_BSUMS);
    int*   boff    = (int*)(ws + OFF_BOFF);

    hipMemsetAsync(counts, 0, N_NODES * sizeof(int), stream);
    hipMemsetAsync(accum, 0, 512 * sizeof(float), stream);

    dim3 gemm_grid((N_NODES + 127) / 128, 2);
    sgemm_xw<<<gemm_grid, 256, 0, stream>>>(x, W, xh);

    att_vec<<<(N_NODES * 64 + 255) / 256, 256, 0, stream>>>(xh, att_src, att_dst,
                                                            a_src, a_dst);

    const int nsb = (N_NODES + 1023) / 1024;   // 98
    count_edges<<<(N_EDGES + 255) / 256, 256, 0, stream>>>(ei, counts);
    scan1<<<nsb, 1024, 0, stream>>>(counts, row_ptr, bsums);
    scan2<<<1, 128, 0, stream>>>(bsums, boff, nsb);
    scan3<<<nsb, 1024, 0, stream>>>(row_ptr, cursor, boff);
    fill_csr<<<(N_EDGES + 255) / 256, 256, 0, stream>>>(ei, cursor, csr_src);

    aggregate<<<N_NODES / 4, 256, 0, stream>>>(
        xh, a_src, a_dst, row_ptr, csr_src, bias, out);

    bn_stats<<<512, 256, 0, stream>>>(out, accum);
    bn_final<<<2048, 256, 0, stream>>>(out, x, accum, gamma, beta);
}

// Round 5
// 649.788 us; speedup vs baseline: 1.6679x; 1.4047x over previous
//
#include <hip/hip_runtime.h>
#include <hip/hip_bf16.h>
#include <math.h>

// GAT layer on MI355X.
// R5 = R4 resubmit (container-level failure last round, kernel never ran).
// bf16 MFMA GEMM for xh (stored bf16-only, 51MB -> L3-resident gathers);
// aggregate: no-max softmax, per-(edge,head) weights computed once in pass A
// and cached in LDS (j+w caches); bn_stats -> two-stage partials.

#define N_NODES 100000
#define N_EDGES 1600000
#define NEG_SLOPE 0.2f
#define BN_EPS  1e-5f

typedef __attribute__((ext_vector_type(8))) short short8;
typedef __attribute__((ext_vector_type(4))) float f32x4;

// ---- workspace layout (bytes) ----
#define OFF_XHB     0            // [N,256] bf16 : 51,200,000
#define OFF_ASRC    51200000     // [N,8] f32
#define OFF_ADST    54400000     // [N,8] f32
#define OFF_ROWPTR  57600000     // [N+1] i32 (padded)
#define OFF_CURSOR  58000256
#define OFF_COUNTS  58400512
#define OFF_CSRSRC  58800768     // [E] i32
#define OFF_ACCUM   65200768     // [512] f32
#define OFF_BSUMS   65202816
#define OFF_BOFF    65203328
#define OFF_WT      65203968     // [256,256] bf16 (W transposed)
#define OFF_PART    65335040     // [2048,512] f32 partials
// total ~69.5 MB

__device__ __forceinline__ float leaky(float v) {
    return v > 0.f ? v : NEG_SLOPE * v;
}
__device__ __forceinline__ unsigned short f2bf(float f) {   // RNE
    unsigned int u = __float_as_uint(f);
    unsigned int r = (u + 0x7fffu + ((u >> 16) & 1u)) >> 16;
    return (unsigned short)r;
}
__device__ __forceinline__ float bf2f(unsigned short u) {
    return __uint_as_float(((unsigned int)u) << 16);
}

// ---------------- W transpose+cast: Wt[n][k] = bf16(W[k][n]) --------------
__global__ __launch_bounds__(256) void castW(const float* __restrict__ W,
                                             unsigned short* __restrict__ Wt) {
    const int k = blockIdx.x;        // 256
    const int n = threadIdx.x;       // 256
    Wt[n * 256 + k] = f2bf(W[k * 256 + n]);
}

// ---------------- GEMM: xhb = bf16(x @ W), MFMA 16x16x32 ------------------
// BM=128, BN=256 (full), BK=32. 256 thr = 4 waves (2x2), wave tile 64x128.
// LDS padded stride 40 bf16 (80B) -> <=2-way bank conflicts (free).
__global__ __launch_bounds__(256) void gemm_mfma(const float* __restrict__ A,
                                                 const unsigned short* __restrict__ Wt,
                                                 unsigned short* __restrict__ xhb) {
    __shared__ unsigned short Asl[2][128 * 40];
    __shared__ unsigned short Bsl[2][256 * 40];
    const int tid = threadIdx.x;
    const int wid = tid >> 6, lane = tid & 63;
    const int wr = wid >> 1, wc = wid & 1;
    const int row0 = blockIdx.x * 128;

    f32x4 acc[4][8];
#pragma unroll
    for (int m = 0; m < 4; ++m)
#pragma unroll
        for (int n = 0; n < 8; ++n) acc[m][n] = (f32x4){0.f, 0.f, 0.f, 0.f};

    float4 areg[4];
    int4 breg[4];

    // ---- prologue: load tile ks=0 ----
#pragma unroll
    for (int q = 0; q < 4; ++q) {
        const int lin = tid + q * 256;
        const int r = lin >> 3, c4 = (lin & 7) * 4;
        const int row = row0 + r;
        areg[q] = (row < N_NODES) ? *(const float4*)&A[(size_t)row * 256 + c4]
                                  : make_float4(0.f, 0.f, 0.f, 0.f);
    }
    {
        const int4* src = (const int4*)&Wt[tid * 256 + 0];
        breg[0] = src[0]; breg[1] = src[1]; breg[2] = src[2]; breg[3] = src[3];
    }
#pragma unroll
    for (int q = 0; q < 4; ++q) {
        const int lin = tid + q * 256;
        const int r = lin >> 3, c4 = (lin & 7) * 4;
        unsigned short* d = &Asl[0][r * 40 + c4];
        d[0] = f2bf(areg[q].x); d[1] = f2bf(areg[q].y);
        d[2] = f2bf(areg[q].z); d[3] = f2bf(areg[q].w);
    }
    {
        int4* d = (int4*)&Bsl[0][tid * 40];
        d[0] = breg[0]; d[1] = breg[1]; d[2] = breg[2]; d[3] = breg[3];
    }
    __syncthreads();

    const int r16 = lane & 15;
    const int k8 = (lane >> 4) * 8;

    int buf = 0;
    for (int ks = 0; ks < 8; ++ks) {
        const bool more = ks < 7;
        if (more) {
            const int kk = (ks + 1) * 32;
#pragma unroll
            for (int q = 0; q < 4; ++q) {
                const int lin = tid + q * 256;
                const int r = lin >> 3, c4 = (lin & 7) * 4;
                const int row = row0 + r;
                areg[q] = (row < N_NODES)
                              ? *(const float4*)&A[(size_t)row * 256 + kk + c4]
                              : make_float4(0.f, 0.f, 0.f, 0.f);
            }
            const int4* src = (const int4*)&Wt[tid * 256 + kk];
            breg[0] = src[0]; breg[1] = src[1]; breg[2] = src[2]; breg[3] = src[3];
        }
        // compute on buf
        short8 afr[4], bfr[8];
#pragma unroll
        for (int m = 0; m < 4; ++m)
            afr[m] = *(const short8*)&Asl[buf][(wr * 64 + m * 16 + r16) * 40 + k8];
#pragma unroll
        for (int n = 0; n < 8; ++n)
            bfr[n] = *(const short8*)&Bsl[buf][(wc * 128 + n * 16 + r16) * 40 + k8];
#pragma unroll
        for (int m = 0; m < 4; ++m)
#pragma unroll
            for (int n = 0; n < 8; ++n)
                acc[m][n] = __builtin_amdgcn_mfma_f32_16x16x32_bf16(
                    afr[m], bfr[n], acc[m][n], 0, 0, 0);
        if (more) {
            const int nb = buf ^ 1;
#pragma unroll
            for (int q = 0; q < 4; ++q) {
                const int lin = tid + q * 256;
                const int r = lin >> 3, c4 = (lin & 7) * 4;
                unsigned short* d = &Asl[nb][r * 40 + c4];
                d[0] = f2bf(areg[q].x); d[1] = f2bf(areg[q].y);
                d[2] = f2bf(areg[q].z); d[3] = f2bf(areg[q].w);
            }
            int4* d = (int4*)&Bsl[nb][tid * 40];
            d[0] = breg[0]; d[1] = breg[1]; d[2] = breg[2]; d[3] = breg[3];
            __syncthreads();
            buf = nb;
        }
    }

    // epilogue: C mapping col=lane&15, row=(lane>>4)*4+reg
#pragma unroll
    for (int m = 0; m < 4; ++m) {
        const int rbase = row0 + wr * 64 + m * 16 + (lane >> 4) * 4;
#pragma unroll
        for (int n = 0; n < 8; ++n) {
            const int col = wc * 128 + n * 16 + r16;
#pragma unroll
            for (int reg = 0; reg < 4; ++reg) {
                const int row = rbase + reg;
                if (row < N_NODES)
                    xhb[(size_t)row * 256 + col] = f2bf(acc[m][n][reg]);
            }
        }
    }
}

// ------------- a_src/a_dst from bf16 xh: one wave per node ----------------
__global__ __launch_bounds__(256) void att_vec(const unsigned short* __restrict__ xhb,
                                               const float* __restrict__ att_src,
                                               const float* __restrict__ att_dst,
                                               float* __restrict__ a_src,
                                               float* __restrict__ a_dst) {
    const int wid = (blockIdx.x * blockDim.x + threadIdx.x) >> 6;
    const int lane = threadIdx.x & 63;
    if (wid >= N_NODES) return;
    const ushort4 xv4 = *(const ushort4*)&xhb[(size_t)wid * 256 + lane * 4];
    const float x0 = bf2f(xv4.x), x1 = bf2f(xv4.y), x2 = bf2f(xv4.z), x3 = bf2f(xv4.w);
    const int h = lane >> 3;
    const int doff = (lane & 7) * 4;
    const float4 sv = *(const float4*)&att_src[h * 32 + doff];
    const float4 dv = *(const float4*)&att_dst[h * 32 + doff];
    float ss = x0 * sv.x + x1 * sv.y + x2 * sv.z + x3 * sv.w;
    float sd = x0 * dv.x + x1 * dv.y + x2 * dv.z + x3 * dv.w;
#pragma unroll
    for (int m = 1; m < 8; m <<= 1) {
        ss += __shfl_xor(ss, m);
        sd += __shfl_xor(sd, m);
    }
    if ((lane & 7) == 0) {
        a_src[wid * 8 + h] = ss;
        a_dst[wid * 8 + h] = sd;
    }
}

// ---------------- CSR build ----------------
__global__ void count_edges(const int* __restrict__ ei, int* __restrict__ counts) {
    const int e = blockIdx.x * blockDim.x + threadIdx.x;
    if (e < N_EDGES) atomicAdd(&counts[ei[N_EDGES + e]], 1);
}

__global__ __launch_bounds__(1024) void scan1(const int* __restrict__ counts,
                                              int* __restrict__ row_ptr,
                                              int* __restrict__ bsums) {
    __shared__ int s[1024];
    const int tid = threadIdx.x;
    const int idx = blockIdx.x * 1024 + tid;
    const int v = (idx < N_NODES) ? counts[idx] : 0;
    s[tid] = v;
    __syncthreads();
#pragma unroll
    for (int off = 1; off < 1024; off <<= 1) {
        const int add = (tid >= off) ? s[tid - off] : 0;
        __syncthreads();
        s[tid] += add;
        __syncthreads();
    }
    if (idx < N_NODES) row_ptr[idx] = s[tid] - v;
    if (tid == 1023) bsums[blockIdx.x] = s[1023];
}

__global__ __launch_bounds__(128) void scan2(const int* __restrict__ bsums,
                                             int* __restrict__ boff, int nb) {
    __shared__ int s[128];
    const int tid = threadIdx.x;
    const int v = (tid < nb) ? bsums[tid] : 0;
    s[tid] = v;
    __syncthreads();
#pragma unroll
    for (int off = 1; off < 128; off <<= 1) {
        const int add = (tid >= off) ? s[tid - off] : 0;
        __syncthreads();
        s[tid] += add;
        __syncthreads();
    }
    if (tid < nb) boff[tid] = s[tid] - v;
}

__global__ __launch_bounds__(1024) void scan3(int* __restrict__ row_ptr,
                                              int* __restrict__ cursor,
                                              const int* __restrict__ boff) {
    const int idx = blockIdx.x * 1024 + threadIdx.x;
    if (idx < N_NODES) {
        const int r = row_ptr[idx] + boff[blockIdx.x];
        row_ptr[idx] = r;
        cursor[idx] = r;
    }
    if (idx == 0) row_ptr[N_NODES] = N_EDGES;
}

__global__ void fill_csr(const int* __restrict__ ei, int* __restrict__ cursor,
                         int* __restrict__ csr_src) {
    const int e = blockIdx.x * blockDim.x + threadIdx.x;
    if (e < N_EDGES) {
        const int s = ei[e];
        const int d = ei[N_EDGES + e];
        const int pos = atomicAdd(&cursor[d], 1);
        csr_src[pos] = s;
    }
}

// ---------------- aggregate: one wave per node ----------------------------
// Pass A: w = exp(leaky(a_src[j]+a_dst[i])) once per (edge,head), cached in
// LDS with j; per-head denominator reduced via shfl. No max subtraction
// (softmax is shift-invariant; logits bounded -> fp32 exp safe).
// Pass B: tight loop: j (LDS) + w (LDS) + 8B bf16 gather + 4 FMA.
__global__ __launch_bounds__(256) void aggregate(const unsigned short* __restrict__ xhb,
                                                 const float* __restrict__ a_src,
                                                 const float* __restrict__ a_dst,
                                                 const int* __restrict__ row_ptr,
                                                 const int* __restrict__ csr_src,
                                                 const float* __restrict__ bias,
                                                 float* __restrict__ outbuf) {
    __shared__ int   j_cache[4][64];
    __shared__ float w_cache[4][64 * 8];
    const int wv = threadIdx.x >> 6;
    const int lane = threadIdx.x & 63;
    const int i = blockIdx.x * 4 + wv;        // grid exact: i < N_NODES
    const int beg = row_ptr[i], end = row_ptr[i + 1];
    const int deg = end - beg;
    const int deg64 = deg < 64 ? deg : 64;

    // ---- pass A ----
    const int h1 = lane & 7, sub = lane >> 3;
    const float ad1 = a_dst[i * 8 + h1];
    float sm_p = (sub == 0) ? __expf(leaky(a_src[i * 8 + h1] + ad1)) : 0.f;
    for (int t = sub; t < deg64; t += 8) {
        const int j = csr_src[beg + t];
        if (h1 == 0) j_cache[wv][t] = j;
        const float w = __expf(leaky(a_src[j * 8 + h1] + ad1));
        w_cache[wv][t * 8 + h1] = w;
        sm_p += w;
    }
#pragma unroll
    for (int m = 8; m < 64; m <<= 1) sm_p += __shfl_xor(sm_p, m);
    __syncthreads();

    // ---- pass B ----
    const int h2 = lane >> 3;
    float sm = __shfl(sm_p, h2);              // denom for head h2 (t<64 + self)
    const float ad2 = a_dst[i * 8 + h2];
    const float as2 = a_src[i * 8 + h2];
    const float wself = __expf(leaky(as2 + ad2));
    const ushort4 sv4 = *(const ushort4*)&xhb[(size_t)i * 256 + lane * 4];
    float4 acc;
    acc.x = wself * bf2f(sv4.x); acc.y = wself * bf2f(sv4.y);
    acc.z = wself * bf2f(sv4.z); acc.w = wself * bf2f(sv4.w);

#pragma unroll 4
    for (int t = 0; t < deg64; ++t) {
        const int j = j_cache[wv][t];
        const float w = w_cache[wv][t * 8 + h2];
        const ushort4 v4 = *(const ushort4*)&xhb[(size_t)j * 256 + lane * 4];
        acc.x = fmaf(w, bf2f(v4.x), acc.x);
        acc.y = fmaf(w, bf2f(v4.y), acc.y);
        acc.z = fmaf(w, bf2f(v4.z), acc.z);
        acc.w = fmaf(w, bf2f(v4.w), acc.w);
    }
    for (int t = 64; t < deg; ++t) {          // rare tail (deg>64)
        const int j = csr_src[beg + t];
        const float w = __expf(leaky(a_src[j * 8 + h2] + ad2));
        sm += w;
        const ushort4 v4 = *(const ushort4*)&xhb[(size_t)j * 256 + lane * 4];
        acc.x = fmaf(w, bf2f(v4.x), acc.x);
        acc.y = fmaf(w, bf2f(v4.y), acc.y);
        acc.z = fmaf(w, bf2f(v4.z), acc.z);
        acc.w = fmaf(w, bf2f(v4.w), acc.w);
    }
    const float inv = 1.0f / sm;
    const float4 bv = *(const float4*)&bias[lane * 4];
    acc.x = acc.x * inv + bv.x;
    acc.y = acc.y * inv + bv.y;
    acc.z = acc.z * inv + bv.z;
    acc.w = acc.w * inv + bv.w;
    *(float4*)&outbuf[(size_t)i * 256 + lane * 4] = acc;
}

// ---------------- BatchNorm stats: two-stage ------------------------------
__global__ __launch_bounds__(256) void bn_stats1(const float* __restrict__ outbuf,
                                                 float* __restrict__ part) {
    const int c = threadIdx.x;
    float s = 0.f, s2 = 0.f;
    for (int r = blockIdx.x; r < N_NODES; r += 2048) {
        const float v = outbuf[(size_t)r * 256 + c];
        s += v; s2 += v * v;
    }
    part[(size_t)blockIdx.x * 512 + c] = s;
    part[(size_t)blockIdx.x * 512 + 256 + c] = s2;
}

__global__ __launch_bounds__(512) void bn_stats2(const float* __restrict__ part,
                                                 float* __restrict__ accum) {
    const int c = threadIdx.x;                 // 0..511
    float s = 0.f;
    for (int b = blockIdx.x; b < 2048; b += 64)
        s += part[(size_t)b * 512 + c];
    atomicAdd(&accum[c], s);
}

// ---------------- BN normalize + residual ---------------------------------
__global__ __launch_bounds__(256) void bn_final(float* __restrict__ out,
                                                const float* __restrict__ x,
                                                const float* __restrict__ accum,
                                                const float* __restrict__ gamma,
                                                const float* __restrict__ beta) {
    const size_t total4 = (size_t)N_NODES * 64;
    const size_t stride = (size_t)gridDim.x * blockDim.x;
    const float invN = 1.0f / (float)N_NODES;
    for (size_t f = blockIdx.x * blockDim.x + threadIdx.x; f < total4; f += stride) {
        const int c4 = ((int)(f & 63)) * 4;
        float4 v = *(float4*)&out[f * 4];
        const float4 xv = *(const float4*)&x[f * 4];
        const float4 sv = *(const float4*)&accum[c4];
        const float4 qv = *(const float4*)&accum[256 + c4];
        const float4 gv = *(const float4*)&gamma[c4];
        const float4 bv = *(const float4*)&beta[c4];
        float mean, var;
        mean = sv.x * invN; var = qv.x * invN - mean * mean;
        v.x = (v.x - mean) * rsqrtf(var + BN_EPS) * gv.x + bv.x + xv.x;
        mean = sv.y * invN; var = qv.y * invN - mean * mean;
        v.y = (v.y - mean) * rsqrtf(var + BN_EPS) * gv.y + bv.y + xv.y;
        mean = sv.z * invN; var = qv.z * invN - mean * mean;
        v.z = (v.z - mean) * rsqrtf(var + BN_EPS) * gv.z + bv.z + xv.z;
        mean = sv.w * invN; var = qv.w * invN - mean * mean;
        v.w = (v.w - mean) * rsqrtf(var + BN_EPS) * gv.w + bv.w + xv.w;
        *(float4*)&out[f * 4] = v;
    }
}

extern "C" void kernel_launch(void* const* d_in, const int* in_sizes, int n_in,
                              void* d_out, int out_size, void* d_ws, size_t ws_size,
                              hipStream_t stream) {
    const float* x       = (const float*)d_in[0];
    const int*   ei      = (const int*)d_in[1];
    const float* W       = (const float*)d_in[2];
    const float* att_src = (const float*)d_in[3];
    const float* att_dst = (const float*)d_in[4];
    const float* bias    = (const float*)d_in[5];
    const float* gamma   = (const float*)d_in[6];
    const float* beta    = (const float*)d_in[7];
    float* out = (float*)d_out;

    char* ws = (char*)d_ws;
    unsigned short* xhb = (unsigned short*)(ws + OFF_XHB);
    float* a_src   = (float*)(ws + OFF_ASRC);
    float* a_dst   = (float*)(ws + OFF_ADST);
    int*   row_ptr = (int*)(ws + OFF_ROWPTR);
    int*   cursor  = (int*)(ws + OFF_CURSOR);
    int*   counts  = (int*)(ws + OFF_COUNTS);
    int*   csr_src = (int*)(ws + OFF_CSRSRC);
    float* accum   = (float*)(ws + OFF_ACCUM);
    int*   bsums   = (int*)(ws + OFF_BSUMS);
    int*   boff    = (int*)(ws + OFF_BOFF);
    unsigned short* Wt = (unsigned short*)(ws + OFF_WT);
    float* part    = (float*)(ws + OFF_PART);

    hipMemsetAsync(counts, 0, N_NODES * sizeof(int), stream);
    hipMemsetAsync(accum, 0, 512 * sizeof(float), stream);

    castW<<<256, 256, 0, stream>>>(W, Wt);
    gemm_mfma<<<(N_NODES + 127) / 128, 256, 0, stream>>>(x, Wt, xhb);

    att_vec<<<(N_NODES * 64 + 255) / 256, 256, 0, stream>>>(xhb, att_src, att_dst,
                                                            a_src, a_dst);

    const int nsb = (N_NODES + 1023) / 1024;   // 98
    count_edges<<<(N_EDGES + 255) / 256, 256, 0, stream>>>(ei, counts);
    scan1<<<nsb, 1024, 0, stream>>>(counts, row_ptr, bsums);
    scan2<<<1, 128, 0, stream>>>(bsums, boff, nsb);
    scan3<<<nsb, 1024, 0, stream>>>(row_ptr, cursor, boff);
    fill_csr<<<(N_EDGES + 255) / 256, 256, 0, stream>>>(ei, cursor, csr_src);

    aggregate<<<N_NODES / 4, 256, 0, stream>>>(
        xhb, a_src, a_dst, row_ptr, csr_src, bias, out);

    bn_stats1<<<2048, 256, 0, stream>>>(out, part);
    bn_stats2<<<64, 512, 0, stream>>>(part, accum);
    bn_final<<<2048, 256, 0, stream>>>(out, x, accum, gamma, beta);
}